// Round 1
// baseline (801.552 us; speedup 1.0000x reference)
//
#include <hip/hip_runtime.h>
#include <stdint.h>

#define M_DIM 8192
#define N_DIM 4096
#define K_DIM 4224
#define BK 64

typedef float f32x4 __attribute__((ext_vector_type(4)));

// ---------------------------------------------------------------------------
// fp4(e2m1) nibble + per-16 E8M0 scale  ->  exact bf8 (e5m2) byte
// nibble n: sign=n>>3, mag m=n&7 in {0,0.5,1,1.5,2,3,4,6}
// value = (1 + 0.5*mantbit) * 2^(14+(m>>1) - 15)  for m>=1
// fold scale 2^(sf-127): exp_field = 14 + (m>>1) + (sf-127)  in [5,23] -> always normal
// ---------------------------------------------------------------------------
__device__ __forceinline__ uint32_t enc_bf8(uint32_t n, int s) {
    uint32_t m = n & 7u;
    uint32_t sign = (n & 8u) << 4;            // 0x80 if negative
    uint32_t mant = ((0xA8u >> m) & 1u) << 1; // mant=2 for m in {3,5,7}
    uint32_t body = ((uint32_t)(int)(14 + (int)(m >> 1) + s) << 2) | mant;
    return sign | (m ? body : 0u);
}

__global__ __launch_bounds__(256) void dequant_bf8(
    const int* __restrict__ packed, const int* __restrict__ sf,
    uint8_t* __restrict__ out, int nblk)
{
    int i = blockIdx.x * 256 + threadIdx.x;
    if (i >= nblk) return;
    const int4* p4 = (const int4*)packed;
    int4 p0 = p4[2 * i];
    int4 p1 = p4[2 * i + 1];
    int s = sf[i] - 127;
    int vv[8] = {p0.x, p0.y, p0.z, p0.w, p1.x, p1.y, p1.z, p1.w};
    uint32_t w[4];
#pragma unroll
    for (int j = 0; j < 4; ++j) {
        uint32_t acc = 0;
#pragma unroll
        for (int h = 0; h < 2; ++h) {
            uint32_t v = (uint32_t)vv[2 * j + h];
            uint32_t b0 = enc_bf8(v & 15u, s);
            uint32_t b1 = enc_bf8((v >> 4) & 15u, s);
            acc |= (b0 | (b1 << 8)) << (16 * h);
        }
        w[j] = acc;
    }
    ((uint4*)out)[i] = make_uint4(w[0], w[1], w[2], w[3]);
}

// ---------------------------------------------------------------------------
// GEMM: C[m][n] = scale * sum_k A[m][k]*B[n][k] + bias[n]
// A: M x K bf8 row-major, B: N x K bf8 row-major (both in workspace)
// 128x128 tile, BK=64, 256 threads = 4 waves in 2x2, each wave 64x64 out
// ---------------------------------------------------------------------------
__global__ __launch_bounds__(256) void gemm_bf8(
    const uint8_t* __restrict__ A, const uint8_t* __restrict__ B,
    const float* __restrict__ scale, const float* __restrict__ bias,
    float* __restrict__ C)
{
    __shared__ uint8_t smem[16384];
    uint8_t* As = smem;           // [128][64]
    uint8_t* Bs = smem + 8192;    // [128][64]

    const int tid  = threadIdx.x;
    const int lane = tid & 63;
    const int w    = tid >> 6;    // wave 0..3
    const int wm   = w >> 1;
    const int wn   = w & 1;
    const int l15  = lane & 15;
    const int q    = lane >> 4;

    const int bn0 = blockIdx.x * 128;
    const int bm0 = blockIdx.y * 128;

    f32x4 acc[4][4];
#pragma unroll
    for (int i = 0; i < 4; ++i)
#pragma unroll
        for (int j = 0; j < 4; ++j)
            acc[i][j] = (f32x4){0.f, 0.f, 0.f, 0.f};

    // staging: wave w stages rows [w*32, w*32+32) of each tile, 2 issues of 16 rows
    const int srow = lane >> 2;          // 0..15
    const int scol = (lane & 3) * 16;    // 0,16,32,48
    const uint8_t* Ag = A + (size_t)(bm0 + w * 32 + srow) * K_DIM + scol;
    const uint8_t* Bg = B + (size_t)(bn0 + w * 32 + srow) * K_DIM + scol;
    uint8_t* Asw = As + w * 2048;        // wave-uniform LDS base
    uint8_t* Bsw = Bs + w * 2048;

    for (int kt = 0; kt < K_DIM / BK; ++kt) {
        const uint8_t* ag = Ag + kt * BK;
        const uint8_t* bg = Bg + kt * BK;
        __syncthreads();  // previous compute done before overwriting LDS
        __builtin_amdgcn_global_load_lds(
            (const __attribute__((address_space(1))) void*)(ag),
            (__attribute__((address_space(3))) void*)(Asw), 16, 0, 0);
        __builtin_amdgcn_global_load_lds(
            (const __attribute__((address_space(1))) void*)(ag + (size_t)16 * K_DIM),
            (__attribute__((address_space(3))) void*)(Asw + 1024), 16, 0, 0);
        __builtin_amdgcn_global_load_lds(
            (const __attribute__((address_space(1))) void*)(bg),
            (__attribute__((address_space(3))) void*)(Bsw), 16, 0, 0);
        __builtin_amdgcn_global_load_lds(
            (const __attribute__((address_space(1))) void*)(bg + (size_t)16 * K_DIM),
            (__attribute__((address_space(3))) void*)(Bsw + 1024), 16, 0, 0);
        __syncthreads();  // compiler drains vmcnt(0) before barrier -> LDS ready

#pragma unroll
        for (int s = 0; s < 2; ++s) {
            long af[4], bf[4];
#pragma unroll
            for (int mt = 0; mt < 4; ++mt)
                af[mt] = *(const long*)(As + (wm * 64 + mt * 16 + l15) * 64 + s * 32 + q * 8);
#pragma unroll
            for (int nt = 0; nt < 4; ++nt)
                bf[nt] = *(const long*)(Bs + (wn * 64 + nt * 16 + l15) * 64 + s * 32 + q * 8);
#pragma unroll
            for (int mt = 0; mt < 4; ++mt)
#pragma unroll
                for (int nt = 0; nt < 4; ++nt)
                    acc[mt][nt] = __builtin_amdgcn_mfma_f32_16x16x32_bf8_bf8(
                        af[mt], bf[nt], acc[mt][nt], 0, 0, 0);
        }
    }

    const float sc = scale[0];
#pragma unroll
    for (int nt = 0; nt < 4; ++nt) {
        const int col = bn0 + wn * 64 + nt * 16 + l15;
        const float bv = bias[col];
#pragma unroll
        for (int mt = 0; mt < 4; ++mt) {
            const int row0 = bm0 + wm * 64 + mt * 16 + q * 4;
#pragma unroll
            for (int i = 0; i < 4; ++i)
                C[(size_t)(row0 + i) * N_DIM + col] = sc * acc[mt][nt][i] + bv;
        }
    }
}

extern "C" void kernel_launch(void* const* d_in, const int* in_sizes, int n_in,
                              void* d_out, int out_size, void* d_ws, size_t ws_size,
                              hipStream_t stream) {
    const int*   A_packed = (const int*)d_in[0];
    const int*   SFA      = (const int*)d_in[1];
    const float* scale    = (const float*)d_in[2];
    const int*   B_packed = (const int*)d_in[3];
    const int*   SFB      = (const int*)d_in[4];
    const float* bias     = (const float*)d_in[5];
    float*       out      = (float*)d_out;

    uint8_t* Abf8 = (uint8_t*)d_ws;                       // M*K bytes = 34,603,008
    uint8_t* Bbf8 = Abf8 + (size_t)M_DIM * K_DIM;         // N*K bytes = 17,301,504

    const int nblkA = M_DIM * K_DIM / 16;  // 2,162,688
    const int nblkB = N_DIM * K_DIM / 16;  // 1,081,344

    dequant_bf8<<<(nblkA + 255) / 256, 256, 0, stream>>>(A_packed, SFA, Abf8, nblkA);
    dequant_bf8<<<(nblkB + 255) / 256, 256, 0, stream>>>(B_packed, SFB, Bbf8, nblkB);

    dim3 grid(N_DIM / 128, M_DIM / 128);   // (32, 64)
    gemm_bf8<<<grid, 256, 0, stream>>>(Abf8, Bbf8, scale, bias, out);
}

// Round 2
// 444.834 us; speedup vs baseline: 1.8019x; 1.8019x over previous
//
#include <hip/hip_runtime.h>
#include <stdint.h>

#define M_DIM 8192
#define N_DIM 4096
#define K_DIM 4224
#define BK 64

typedef float f32x4 __attribute__((ext_vector_type(4)));
typedef long  i64x2 __attribute__((ext_vector_type(2)));

// ---------------------------------------------------------------------------
// fp4(e2m1) nibble -> bf8(e5m2) with exponent bias folded later.
// nibble n: sign=n>>3, mag m=n&7 in {0,0.5,1,1.5,2,3,4,6}
// baseline (s=0) byte: sign | ((14 + (m>>1))<<2) | mant2   (0 if m==0)
// folding scale 2^s: add s<<2 to byte iff m!=0. exp field stays in [5,23]:
// no carry/borrow across byte boundaries for s in [-9,6].
// ---------------------------------------------------------------------------
__device__ __forceinline__ uint32_t enc_base(uint32_t n) {
    uint32_t m = n & 7u;
    uint32_t sign = (n & 8u) << 4;
    uint32_t mant = ((0xA8u >> m) & 1u) << 1;       // mant=2 for m in {3,5,7}
    uint32_t body = ((14u + (m >> 1)) << 2) | mant;
    return sign | (m ? body : 0u);
}

// Dequant + K-interleave: within each 64-byte k-block, plain byte p maps to
//   p<32  -> dest 16*(p/8)   + p%8
//   p>=32 -> dest 16*((p-32)/8) + 8 + p%8
// so a ds_read_b128 at row*64+q*16 yields k=q*8..q*8+7 (lo) and k=32+q*8..+7 (hi).
// One thread = one scale block (16 fp4 -> 16 bf8 bytes = two 8B chunks).
__global__ __launch_bounds__(256) void dequant_bf8(
    const int* __restrict__ packed, const int* __restrict__ sf,
    uint8_t* __restrict__ out, int nblk)
{
    __shared__ uint32_t lut[256];
    {
        uint32_t b = threadIdx.x;
        uint32_t v0 = enc_base(b & 15u), v1 = enc_base(b >> 4);
        uint32_t mask = ((b & 7u) ? 1u : 0u) | (((b >> 4) & 7u) ? 0x100u : 0u);
        lut[b] = (v0 | (v1 << 8)) | (mask << 16);
    }
    __syncthreads();

    int i = blockIdx.x * 256 + threadIdx.x;
    if (i >= nblk) return;
    const int4* p4 = (const int4*)packed;
    int4 p0 = p4[2 * i];
    int4 p1 = p4[2 * i + 1];
    int s4 = (sf[i] - 127) << 2;

    int vv[8] = {p0.x, p0.y, p0.z, p0.w, p1.x, p1.y, p1.z, p1.w};
    uint32_t w[4];
#pragma unroll
    for (int j = 0; j < 4; ++j) {
        uint32_t e0 = lut[vv[2 * j] & 0xFF];
        uint32_t e1 = lut[vv[2 * j + 1] & 0xFF];
        int v0 = (int)(e0 & 0xFFFFu) + (int)(e0 >> 16) * s4;
        int v1 = (int)(e1 & 0xFFFFu) + (int)(e1 >> 16) * s4;
        w[j] = (uint32_t)(v0 & 0xFFFF) | ((uint32_t)v1 << 16);
    }

    // interleaved destination: row r, 64-block t64, scale-block t within it
    const int per_row = K_DIM / 16;            // 264 (multiple of 4)
    int r   = i / per_row;
    int rem = i - r * per_row;
    int t64 = rem >> 2;
    int t   = i & 3;
    int off = ((t & 1) << 5) + ((t >> 1) << 3); // {0,32,8,40}
    uint8_t* base = out + (size_t)r * K_DIM + t64 * 64 + off;
    *(uint2*)(base)      = make_uint2(w[0], w[1]);  // first 8 bytes
    *(uint2*)(base + 16) = make_uint2(w[2], w[3]);  // second 8 bytes
}

// ---------------------------------------------------------------------------
// GEMM: C[m][n] = scale * sum_k A[m][k]*B[n][k] + bias[n]
// A: M x K bf8 (k-interleaved per 64-block), B: N x K same. 128x128 tile,
// BK=64 bytes, 256 threads = 4 waves (2x2), each wave 64x64 output.
// ---------------------------------------------------------------------------
__global__ __launch_bounds__(256) void gemm_bf8(
    const uint8_t* __restrict__ A, const uint8_t* __restrict__ B,
    const float* __restrict__ scale, const float* __restrict__ bias,
    float* __restrict__ C)
{
    __shared__ uint8_t smem[16384];
    uint8_t* As = smem;           // [128][64]
    uint8_t* Bs = smem + 8192;    // [128][64]

    const int tid  = threadIdx.x;
    const int lane = tid & 63;
    const int w    = tid >> 6;
    const int wm   = w >> 1;
    const int wn   = w & 1;
    const int l15  = lane & 15;
    const int q    = lane >> 4;

    const int bn0 = blockIdx.x * 128;
    const int bm0 = blockIdx.y * 128;

    f32x4 acc[4][4];
#pragma unroll
    for (int i = 0; i < 4; ++i)
#pragma unroll
        for (int j = 0; j < 4; ++j)
            acc[i][j] = (f32x4){0.f, 0.f, 0.f, 0.f};

    const int srow = lane >> 2;
    const int scol = (lane & 3) * 16;
    const uint8_t* Ag = A + (size_t)(bm0 + w * 32 + srow) * K_DIM + scol;
    const uint8_t* Bg = B + (size_t)(bn0 + w * 32 + srow) * K_DIM + scol;
    uint8_t* Asw = As + w * 2048;
    uint8_t* Bsw = Bs + w * 2048;

    for (int kt = 0; kt < K_DIM / BK; ++kt) {
        const uint8_t* ag = Ag + kt * BK;
        const uint8_t* bg = Bg + kt * BK;
        __syncthreads();
        __builtin_amdgcn_global_load_lds(
            (const __attribute__((address_space(1))) void*)(ag),
            (__attribute__((address_space(3))) void*)(Asw), 16, 0, 0);
        __builtin_amdgcn_global_load_lds(
            (const __attribute__((address_space(1))) void*)(ag + (size_t)16 * K_DIM),
            (__attribute__((address_space(3))) void*)(Asw + 1024), 16, 0, 0);
        __builtin_amdgcn_global_load_lds(
            (const __attribute__((address_space(1))) void*)(bg),
            (__attribute__((address_space(3))) void*)(Bsw), 16, 0, 0);
        __builtin_amdgcn_global_load_lds(
            (const __attribute__((address_space(1))) void*)(bg + (size_t)16 * K_DIM),
            (__attribute__((address_space(3))) void*)(Bsw + 1024), 16, 0, 0);
        __syncthreads();

        // one ds_read_b128 per fragment-pair: lo 8B = k-step 0, hi 8B = k-step 1
        i64x2 a2[4], b2[4];
#pragma unroll
        for (int mt = 0; mt < 4; ++mt)
            a2[mt] = *(const i64x2*)(As + (wm * 64 + mt * 16 + l15) * 64 + q * 16);
#pragma unroll
        for (int nt = 0; nt < 4; ++nt)
            b2[nt] = *(const i64x2*)(Bs + (wn * 64 + nt * 16 + l15) * 64 + q * 16);

#pragma unroll
        for (int mt = 0; mt < 4; ++mt)
#pragma unroll
            for (int nt = 0; nt < 4; ++nt)
                acc[mt][nt] = __builtin_amdgcn_mfma_f32_16x16x32_bf8_bf8(
                    a2[mt].x, b2[nt].x, acc[mt][nt], 0, 0, 0);
#pragma unroll
        for (int mt = 0; mt < 4; ++mt)
#pragma unroll
            for (int nt = 0; nt < 4; ++nt)
                acc[mt][nt] = __builtin_amdgcn_mfma_f32_16x16x32_bf8_bf8(
                    a2[mt].y, b2[nt].y, acc[mt][nt], 0, 0, 0);
    }

    const float sc = scale[0];
#pragma unroll
    for (int nt = 0; nt < 4; ++nt) {
        const int col = bn0 + wn * 64 + nt * 16 + l15;
        const float bv = bias[col];
#pragma unroll
        for (int mt = 0; mt < 4; ++mt) {
            const int row0 = bm0 + wm * 64 + mt * 16 + q * 4;
#pragma unroll
            for (int i = 0; i < 4; ++i)
                C[(size_t)(row0 + i) * N_DIM + col] = sc * acc[mt][nt][i] + bv;
        }
    }
}

extern "C" void kernel_launch(void* const* d_in, const int* in_sizes, int n_in,
                              void* d_out, int out_size, void* d_ws, size_t ws_size,
                              hipStream_t stream) {
    const int*   A_packed = (const int*)d_in[0];
    const int*   SFA      = (const int*)d_in[1];
    const float* scale    = (const float*)d_in[2];
    const int*   B_packed = (const int*)d_in[3];
    const int*   SFB      = (const int*)d_in[4];
    const float* bias     = (const float*)d_in[5];
    float*       out      = (float*)d_out;

    uint8_t* Abf8 = (uint8_t*)d_ws;
    uint8_t* Bbf8 = Abf8 + (size_t)M_DIM * K_DIM;

    const int nblkA = M_DIM * K_DIM / 16;
    const int nblkB = N_DIM * K_DIM / 16;

    dequant_bf8<<<(nblkA + 255) / 256, 256, 0, stream>>>(A_packed, SFA, Abf8, nblkA);
    dequant_bf8<<<(nblkB + 255) / 256, 256, 0, stream>>>(B_packed, SFB, Bbf8, nblkB);

    dim3 grid(N_DIM / 128, M_DIM / 128);
    gemm_bf8<<<grid, 256, 0, stream>>>(Abf8, Bbf8, scale, bias, out);
}

// Round 3
// 408.142 us; speedup vs baseline: 1.9639x; 1.0899x over previous
//
#include <hip/hip_runtime.h>
#include <stdint.h>

#define M_DIM 8192
#define N_DIM 4096
#define K_DIM 4224
#define BK 64

typedef float f32x16 __attribute__((ext_vector_type(16)));
typedef int   i32x8  __attribute__((ext_vector_type(8)));
typedef int   i32x4  __attribute__((ext_vector_type(4)));

// ---------------------------------------------------------------------------
// fp4(e2m1) nibble + per-16 E8M0 scale -> exact bf8(e5m2), pure VALU.
// base byte for mag m in {0..7}: {0x00,0x38,0x3C,0x3E,0x40,0x42,0x44,0x46}
// scale fold: byte += s4 (= (sf-127)<<2) iff m!=0; exp field stays in [5,23].
// Packed-carry-safe form: base + nz*(s4+64) - nz*64 per byte (range [0x14,0x9E]).
// ---------------------------------------------------------------------------
__device__ __forceinline__ uint32_t conv4(uint32_t x, uint32_t k1) {
    uint32_t n7   = x & 0x07070707u;
    uint32_t base = __builtin_amdgcn_perm(0x46444240u, 0x3E3C3800u, n7);
    uint32_t nz   = __builtin_amdgcn_perm(0x01010101u, 0x01010100u, n7);
    uint32_t sign = (x & 0x08080808u) << 4;
    return (base + nz * k1 - (nz << 6)) | sign;
}

// One thread = one 16-element scale block: 8 int32 in (1 byte each), 16 bf8 out.
// A blocks first (8448 full wavefront-uniform blocks), then B.
__global__ __launch_bounds__(256) void dequant_all(
    const int* __restrict__ Ap, const int* __restrict__ SFA, uint8_t* __restrict__ Aout,
    const int* __restrict__ Bp, const int* __restrict__ SFB, uint8_t* __restrict__ Bout)
{
    const int nblkA = M_DIM * K_DIM / 16;
    int i = blockIdx.x * 256 + threadIdx.x;
    const int* p; const int* sf; uint8_t* out; int idx;
    if (i < nblkA) { p = Ap; sf = SFA; out = Aout; idx = i; }
    else           { p = Bp; sf = SFB; out = Bout; idx = i - nblkA; }

    const int4* p4 = (const int4*)p;
    int4 p0 = p4[2 * idx];
    int4 p1 = p4[2 * idx + 1];
    int s4 = (sf[idx] - 127) << 2;
    uint32_t k1 = (uint32_t)(s4 + 64);

    uint32_t o[4];
#pragma unroll
    for (int g = 0; g < 2; ++g) {
        int4 pg = g ? p1 : p0;
        uint32_t w = (uint32_t)(pg.x & 0xFF) | ((uint32_t)(pg.y & 0xFF) << 8) |
                     ((uint32_t)(pg.z & 0xFF) << 16) | ((uint32_t)pg.w << 24);
        uint32_t lr = conv4(w & 0x0F0F0F0Fu, k1);
        uint32_t hr = conv4((w >> 4) & 0x0F0F0F0Fu, k1);
        o[2 * g]     = __builtin_amdgcn_perm(hr, lr, 0x05010400u); // elems 0..3
        o[2 * g + 1] = __builtin_amdgcn_perm(hr, lr, 0x07030602u); // elems 4..7
    }
    *(uint4*)(out + (size_t)idx * 16) = make_uint4(o[0], o[1], o[2], o[3]);
}

// ---------------------------------------------------------------------------
// GEMM via MX-scaled MFMA at unity scale: C = scale*(A.B^T) + bias
// A: M x K bf8 row-major (plain k order), B: N x K same.
// 128x128 tile, BK=64, 256 threads = 4 waves (2x2), wave = 64x64 out
// = 2x2 tiles of v_mfma_scale_f32_32x32x64_f8f6f4 (FMT=bf8, scales=0x7F).
// ---------------------------------------------------------------------------
__global__ __launch_bounds__(256) void gemm_mx(
    const uint8_t* __restrict__ A, const uint8_t* __restrict__ B,
    const float* __restrict__ scale, const float* __restrict__ bias,
    float* __restrict__ C)
{
    __shared__ uint8_t smem[16384];
    uint8_t* As = smem;           // [128][64]
    uint8_t* Bs = smem + 8192;    // [128][64]

    const int tid  = threadIdx.x;
    const int lane = tid & 63;
    const int w    = tid >> 6;
    const int wm   = w >> 1;
    const int wn   = w & 1;
    const int r31  = lane & 31;
    const int h    = lane >> 5;

    const int bn0 = blockIdx.x * 128;
    const int bm0 = blockIdx.y * 128;

    f32x16 acc[2][2];
#pragma unroll
    for (int i = 0; i < 2; ++i)
#pragma unroll
        for (int j = 0; j < 2; ++j)
            acc[i][j] = (f32x16)(0.0f);

    // staging: wave w stages rows [w*32, w*32+32), 2 issues of 16 rows x 64B
    const int srow = lane >> 2;
    const int scol = (lane & 3) * 16;
    const uint8_t* Ag = A + (size_t)(bm0 + w * 32 + srow) * K_DIM + scol;
    const uint8_t* Bg = B + (size_t)(bn0 + w * 32 + srow) * K_DIM + scol;
    uint8_t* Asw = As + w * 2048;
    uint8_t* Bsw = Bs + w * 2048;

    for (int kt = 0; kt < K_DIM / BK; ++kt) {
        const uint8_t* ag = Ag + kt * BK;
        const uint8_t* bg = Bg + kt * BK;
        __syncthreads();
        __builtin_amdgcn_global_load_lds(
            (const __attribute__((address_space(1))) void*)(ag),
            (__attribute__((address_space(3))) void*)(Asw), 16, 0, 0);
        __builtin_amdgcn_global_load_lds(
            (const __attribute__((address_space(1))) void*)(ag + (size_t)16 * K_DIM),
            (__attribute__((address_space(3))) void*)(Asw + 1024), 16, 0, 0);
        __builtin_amdgcn_global_load_lds(
            (const __attribute__((address_space(1))) void*)(bg),
            (__attribute__((address_space(3))) void*)(Bsw), 16, 0, 0);
        __builtin_amdgcn_global_load_lds(
            (const __attribute__((address_space(1))) void*)(bg + (size_t)16 * K_DIM),
            (__attribute__((address_space(3))) void*)(Bsw + 1024), 16, 0, 0);
        __syncthreads();

        // fragment: lane holds k = h*32 .. h*32+31 (32 contiguous bytes) of its row
        i32x8 af[2], bf[2];
#pragma unroll
        for (int mi = 0; mi < 2; ++mi) {
            const uint8_t* pa = As + (wm * 64 + mi * 32 + r31) * 64 + h * 32;
            i32x4 lo = *(const i32x4*)pa;
            i32x4 hi = *(const i32x4*)(pa + 16);
            af[mi] = __builtin_shufflevector(lo, hi, 0, 1, 2, 3, 4, 5, 6, 7);
        }
#pragma unroll
        for (int ni = 0; ni < 2; ++ni) {
            const uint8_t* pb = Bs + (wn * 64 + ni * 32 + r31) * 64 + h * 32;
            i32x4 lo = *(const i32x4*)pb;
            i32x4 hi = *(const i32x4*)(pb + 16);
            bf[ni] = __builtin_shufflevector(lo, hi, 0, 1, 2, 3, 4, 5, 6, 7);
        }

#pragma unroll
        for (int mi = 0; mi < 2; ++mi)
#pragma unroll
            for (int ni = 0; ni < 2; ++ni)
                acc[mi][ni] = __builtin_amdgcn_mfma_scale_f32_32x32x64_f8f6f4(
                    af[mi], bf[ni], acc[mi][ni],
                    1, 1,                 // cbsz=bf8(e5m2), blgp=bf8(e5m2)
                    0, 0x7F7F7F7F,        // scale A = 2^0
                    0, 0x7F7F7F7F);       // scale B = 2^0
    }

    const float sc = scale[0];
#pragma unroll
    for (int ni = 0; ni < 2; ++ni) {
        const int col = bn0 + wn * 64 + ni * 32 + r31;
        const float bv = bias[col];
#pragma unroll
        for (int mi = 0; mi < 2; ++mi) {
            const int rbase = bm0 + wm * 64 + mi * 32 + 4 * h;
#pragma unroll
            for (int reg = 0; reg < 16; ++reg) {
                const int row = rbase + (reg & 3) + 8 * (reg >> 2);
                C[(size_t)row * N_DIM + col] = sc * acc[mi][ni][reg] + bv;
            }
        }
    }
}

extern "C" void kernel_launch(void* const* d_in, const int* in_sizes, int n_in,
                              void* d_out, int out_size, void* d_ws, size_t ws_size,
                              hipStream_t stream) {
    const int*   A_packed = (const int*)d_in[0];
    const int*   SFA      = (const int*)d_in[1];
    const float* scale    = (const float*)d_in[2];
    const int*   B_packed = (const int*)d_in[3];
    const int*   SFB      = (const int*)d_in[4];
    const float* bias     = (const float*)d_in[5];
    float*       out      = (float*)d_out;

    uint8_t* Abf8 = (uint8_t*)d_ws;
    uint8_t* Bbf8 = Abf8 + (size_t)M_DIM * K_DIM;

    const int nblkA = M_DIM * K_DIM / 16;   // 2,162,688 (8448 blocks)
    const int nblkB = N_DIM * K_DIM / 16;   // 1,081,344 (4224 blocks)
    dequant_all<<<(nblkA + nblkB) / 256, 256, 0, stream>>>(
        A_packed, SFA, Abf8, B_packed, SFB, Bbf8);

    dim3 grid(N_DIM / 128, M_DIM / 128);
    gemm_mx<<<grid, 256, 0, stream>>>(Abf8, Bbf8, scale, bias, out);
}

// Round 4
// 384.964 us; speedup vs baseline: 2.0821x; 1.0602x over previous
//
#include <hip/hip_runtime.h>
#include <stdint.h>

#define M_DIM 8192
#define N_DIM 4096
#define K_DIM 4224
#define BK 64

typedef float f32x16 __attribute__((ext_vector_type(16)));
typedef int   i32x8  __attribute__((ext_vector_type(8)));
typedef int   i32x4  __attribute__((ext_vector_type(4)));

// ---------------------------------------------------------------------------
// fp4(e2m1) nibble + per-16 E8M0 scale -> exact bf8(e5m2), pure VALU.
// base byte for mag m in {0..7}: {0x00,0x38,0x3C,0x3E,0x40,0x42,0x44,0x46}
// scale fold: byte += s4 (= (sf-127)<<2) iff m!=0; exp field stays in [5,23].
// Packed-carry-safe form: base + nz*(s4+64) - nz*64 per byte (range [0x14,0x9E]).
// ---------------------------------------------------------------------------
__device__ __forceinline__ uint32_t conv4(uint32_t x, uint32_t k1) {
    uint32_t n7   = x & 0x07070707u;
    uint32_t base = __builtin_amdgcn_perm(0x46444240u, 0x3E3C3800u, n7);
    uint32_t nz   = __builtin_amdgcn_perm(0x01010101u, 0x01010100u, n7);
    uint32_t sign = (x & 0x08080808u) << 4;
    return (base + nz * k1 - (nz << 6)) | sign;
}

__global__ __launch_bounds__(256) void dequant_all(
    const int* __restrict__ Ap, const int* __restrict__ SFA, uint8_t* __restrict__ Aout,
    const int* __restrict__ Bp, const int* __restrict__ SFB, uint8_t* __restrict__ Bout)
{
    const int nblkA = M_DIM * K_DIM / 16;
    int i = blockIdx.x * 256 + threadIdx.x;
    const int* p; const int* sf; uint8_t* out; int idx;
    if (i < nblkA) { p = Ap; sf = SFA; out = Aout; idx = i; }
    else           { p = Bp; sf = SFB; out = Bout; idx = i - nblkA; }

    const int4* p4 = (const int4*)p;
    int4 p0 = p4[2 * idx];
    int4 p1 = p4[2 * idx + 1];
    int s4 = (sf[idx] - 127) << 2;
    uint32_t k1 = (uint32_t)(s4 + 64);

    uint32_t o[4];
#pragma unroll
    for (int g = 0; g < 2; ++g) {
        int4 pg = g ? p1 : p0;
        uint32_t w = (uint32_t)(pg.x & 0xFF) | ((uint32_t)(pg.y & 0xFF) << 8) |
                     ((uint32_t)(pg.z & 0xFF) << 16) | ((uint32_t)pg.w << 24);
        uint32_t lr = conv4(w & 0x0F0F0F0Fu, k1);
        uint32_t hr = conv4((w >> 4) & 0x0F0F0F0Fu, k1);
        o[2 * g]     = __builtin_amdgcn_perm(hr, lr, 0x05010400u); // elems 0..3
        o[2 * g + 1] = __builtin_amdgcn_perm(hr, lr, 0x07030602u); // elems 4..7
    }
    *(uint4*)(out + (size_t)idx * 16) = make_uint4(o[0], o[1], o[2], o[3]);
}

// ---------------------------------------------------------------------------
// GEMM via MX-scaled MFMA at unity scale: C = scale*(A.B^T) + bias
// LDS layout XOR-swizzle: 16B granule (row, g) lives at slot g ^ ((row>>1)&3).
// Makes every ds_read_b128 fragment load conflict-free (banks 16r+4*((r>>1)&3^g)
// cover all 32 banks exactly once per 8 rows). Staging permutes which granule
// each lane fetches (same 64B segments -> still fully coalesced).
// ---------------------------------------------------------------------------
__global__ __launch_bounds__(256) void gemm_mx(
    const uint8_t* __restrict__ A, const uint8_t* __restrict__ B,
    const float* __restrict__ scale, const float* __restrict__ bias,
    float* __restrict__ C)
{
    __shared__ uint8_t smem[16384];
    uint8_t* As = smem;           // [128][64] (granule-swizzled)
    uint8_t* Bs = smem + 8192;    // [128][64]

    const int tid  = threadIdx.x;
    const int lane = tid & 63;
    const int w    = tid >> 6;
    const int wm   = w >> 1;
    const int wn   = w & 1;
    const int r31  = lane & 31;
    const int h    = lane >> 5;

    const int bn0 = blockIdx.x * 128;
    const int bm0 = blockIdx.y * 128;

    f32x16 acc[2][2];
#pragma unroll
    for (int i = 0; i < 2; ++i)
#pragma unroll
        for (int j = 0; j < 2; ++j)
            acc[i][j] = (f32x16)(0.0f);

    // staging: wave w stages rows [w*32, w*32+32), 2 issues of 16 rows x 64B.
    // lane slot = local_row*4 + g''; fetch global granule g = g'' ^ ((row>>1)&3)
    const int srow = lane >> 2;
    const int scol = (((lane & 3) ^ ((lane >> 3) & 3)) << 4);
    const uint8_t* Ag = A + (size_t)(bm0 + w * 32 + srow) * K_DIM + scol;
    const uint8_t* Bg = B + (size_t)(bn0 + w * 32 + srow) * K_DIM + scol;
    uint8_t* Asw = As + w * 2048;
    uint8_t* Bsw = Bs + w * 2048;

    // swizzled, kt-invariant fragment addresses (hoisted out of the K-loop)
    const int sx = (r31 >> 1) & 3;
    const uint8_t* pa_lo[2]; const uint8_t* pa_hi[2];
    const uint8_t* pb_lo[2]; const uint8_t* pb_hi[2];
#pragma unroll
    for (int mi = 0; mi < 2; ++mi) {
        const uint8_t* base = As + (wm * 64 + mi * 32 + r31) * 64;
        pa_lo[mi] = base + (((2 * h)     ^ sx) << 4);
        pa_hi[mi] = base + (((2 * h + 1) ^ sx) << 4);
    }
#pragma unroll
    for (int ni = 0; ni < 2; ++ni) {
        const uint8_t* base = Bs + (wn * 64 + ni * 32 + r31) * 64;
        pb_lo[ni] = base + (((2 * h)     ^ sx) << 4);
        pb_hi[ni] = base + (((2 * h + 1) ^ sx) << 4);
    }

    for (int kt = 0; kt < K_DIM / BK; ++kt) {
        const uint8_t* ag = Ag + kt * BK;
        const uint8_t* bg = Bg + kt * BK;
        __syncthreads();
        __builtin_amdgcn_global_load_lds(
            (const __attribute__((address_space(1))) void*)(ag),
            (__attribute__((address_space(3))) void*)(Asw), 16, 0, 0);
        __builtin_amdgcn_global_load_lds(
            (const __attribute__((address_space(1))) void*)(ag + (size_t)16 * K_DIM),
            (__attribute__((address_space(3))) void*)(Asw + 1024), 16, 0, 0);
        __builtin_amdgcn_global_load_lds(
            (const __attribute__((address_space(1))) void*)(bg),
            (__attribute__((address_space(3))) void*)(Bsw), 16, 0, 0);
        __builtin_amdgcn_global_load_lds(
            (const __attribute__((address_space(1))) void*)(bg + (size_t)16 * K_DIM),
            (__attribute__((address_space(3))) void*)(Bsw + 1024), 16, 0, 0);
        __syncthreads();

        i32x8 af[2], bf[2];
#pragma unroll
        for (int mi = 0; mi < 2; ++mi) {
            i32x4 lo = *(const i32x4*)pa_lo[mi];
            i32x4 hi = *(const i32x4*)pa_hi[mi];
            af[mi] = __builtin_shufflevector(lo, hi, 0, 1, 2, 3, 4, 5, 6, 7);
        }
#pragma unroll
        for (int ni = 0; ni < 2; ++ni) {
            i32x4 lo = *(const i32x4*)pb_lo[ni];
            i32x4 hi = *(const i32x4*)pb_hi[ni];
            bf[ni] = __builtin_shufflevector(lo, hi, 0, 1, 2, 3, 4, 5, 6, 7);
        }

#pragma unroll
        for (int mi = 0; mi < 2; ++mi)
#pragma unroll
            for (int ni = 0; ni < 2; ++ni)
                acc[mi][ni] = __builtin_amdgcn_mfma_scale_f32_32x32x64_f8f6f4(
                    af[mi], bf[ni], acc[mi][ni],
                    1, 1,                 // cbsz=bf8(e5m2), blgp=bf8(e5m2)
                    0, 0x7F7F7F7F,        // scale A = 2^0
                    0, 0x7F7F7F7F);       // scale B = 2^0
    }

    const float sc = scale[0];
#pragma unroll
    for (int ni = 0; ni < 2; ++ni) {
        const int col = bn0 + wn * 64 + ni * 32 + r31;
        const float bv = bias[col];
#pragma unroll
        for (int mi = 0; mi < 2; ++mi) {
            const int rbase = bm0 + wm * 64 + mi * 32 + 4 * h;
#pragma unroll
            for (int reg = 0; reg < 16; ++reg) {
                const int row = rbase + (reg & 3) + 8 * (reg >> 2);
                C[(size_t)row * N_DIM + col] = sc * acc[mi][ni][reg] + bv;
            }
        }
    }
}

extern "C" void kernel_launch(void* const* d_in, const int* in_sizes, int n_in,
                              void* d_out, int out_size, void* d_ws, size_t ws_size,
                              hipStream_t stream) {
    const int*   A_packed = (const int*)d_in[0];
    const int*   SFA      = (const int*)d_in[1];
    const float* scale    = (const float*)d_in[2];
    const int*   B_packed = (const int*)d_in[3];
    const int*   SFB      = (const int*)d_in[4];
    const float* bias     = (const float*)d_in[5];
    float*       out      = (float*)d_out;

    uint8_t* Abf8 = (uint8_t*)d_ws;
    uint8_t* Bbf8 = Abf8 + (size_t)M_DIM * K_DIM;

    const int nblkA = M_DIM * K_DIM / 16;   // 2,162,688 (8448 blocks of 256)
    const int nblkB = N_DIM * K_DIM / 16;   // 1,081,344 (4224 blocks)
    dequant_all<<<(nblkA + nblkB) / 256, 256, 0, stream>>>(
        A_packed, SFA, Abf8, B_packed, SFB, Bbf8);

    dim3 grid(N_DIM / 128, M_DIM / 128);
    gemm_mx<<<grid, 256, 0, stream>>>(Abf8, Bbf8, scale, bias, out);
}

// Round 5
// 370.730 us; speedup vs baseline: 2.1621x; 1.0384x over previous
//
#include <hip/hip_runtime.h>
#include <stdint.h>

#define M_DIM 8192
#define N_DIM 4096
#define K_DIM 4224
#define BK 64

typedef float f32x16 __attribute__((ext_vector_type(16)));
typedef int   i32x8  __attribute__((ext_vector_type(8)));
typedef int   i32x4  __attribute__((ext_vector_type(4)));

#define RAW_BARRIER()  asm volatile("s_barrier" ::: "memory")
#define WAIT_VM4()     asm volatile("s_waitcnt vmcnt(4)" ::: "memory")
#define WAIT_VM0()     asm volatile("s_waitcnt vmcnt(0)" ::: "memory")

// ---------------------------------------------------------------------------
// fp4(e2m1) nibble + per-16 E8M0 scale -> exact bf8(e5m2), pure VALU.
// base byte for mag m in {0..7}: {0x00,0x38,0x3C,0x3E,0x40,0x42,0x44,0x46}
// scale fold: byte += s4 (= (sf-127)<<2) iff m!=0; exp field stays in [5,23].
// Packed-carry-safe form: base + nz*(s4+64) - nz*64 per byte (range [0x14,0x9E]).
// ---------------------------------------------------------------------------
__device__ __forceinline__ uint32_t conv4(uint32_t x, uint32_t k1) {
    uint32_t n7   = x & 0x07070707u;
    uint32_t base = __builtin_amdgcn_perm(0x46444240u, 0x3E3C3800u, n7);
    uint32_t nz   = __builtin_amdgcn_perm(0x01010101u, 0x01010100u, n7);
    uint32_t sign = (x & 0x08080808u) << 4;
    return (base + nz * k1 - (nz << 6)) | sign;
}

__global__ __launch_bounds__(256) void dequant_all(
    const int* __restrict__ Ap, const int* __restrict__ SFA, uint8_t* __restrict__ Aout,
    const int* __restrict__ Bp, const int* __restrict__ SFB, uint8_t* __restrict__ Bout)
{
    const int nblkA = M_DIM * K_DIM / 16;
    int i = blockIdx.x * 256 + threadIdx.x;
    const int* p; const int* sf; uint8_t* out; int idx;
    if (i < nblkA) { p = Ap; sf = SFA; out = Aout; idx = i; }
    else           { p = Bp; sf = SFB; out = Bout; idx = i - nblkA; }

    const int4* p4 = (const int4*)p;
    int4 p0 = p4[2 * idx];
    int4 p1 = p4[2 * idx + 1];
    int s4 = (sf[idx] - 127) << 2;
    uint32_t k1 = (uint32_t)(s4 + 64);

    uint32_t o[4];
#pragma unroll
    for (int g = 0; g < 2; ++g) {
        int4 pg = g ? p1 : p0;
        uint32_t w = (uint32_t)(pg.x & 0xFF) | ((uint32_t)(pg.y & 0xFF) << 8) |
                     ((uint32_t)(pg.z & 0xFF) << 16) | ((uint32_t)pg.w << 24);
        uint32_t lr = conv4(w & 0x0F0F0F0Fu, k1);
        uint32_t hr = conv4((w >> 4) & 0x0F0F0F0Fu, k1);
        o[2 * g]     = __builtin_amdgcn_perm(hr, lr, 0x05010400u); // elems 0..3
        o[2 * g + 1] = __builtin_amdgcn_perm(hr, lr, 0x07030602u); // elems 4..7
    }
    *(uint4*)(out + (size_t)idx * 16) = make_uint4(o[0], o[1], o[2], o[3]);
}

// ---------------------------------------------------------------------------
// GEMM via MX-scaled MFMA at unity scale: C = scale*(A.B^T) + bias
// - XOR-swizzled LDS granules (16B granule (row,g) at slot g^((row>>1)&3)):
//   conflict-free b128 fragment reads; staging stays coalesced.
// - Double-buffered LDS (2 x 16KB) + RAW s_barrier + per-wave vmcnt(4):
//   each wave owns exactly 4 global_load_lds per tile; prefetch of tile t+1
//   stays in flight across the barrier while tile t is computed (no vmcnt(0)
//   drain — the m97-structure stall).
// ---------------------------------------------------------------------------
__global__ __launch_bounds__(256) void gemm_mx(
    const uint8_t* __restrict__ A, const uint8_t* __restrict__ B,
    const float* __restrict__ scale, const float* __restrict__ bias,
    float* __restrict__ C)
{
    __shared__ uint8_t smem[32768];
    uint8_t* As = smem;            // buf0: A [128][64], B at +8192; buf1 at +16384
    uint8_t* Bs = smem + 8192;

    const int tid  = threadIdx.x;
    const int lane = tid & 63;
    const int w    = tid >> 6;
    const int wm   = w >> 1;
    const int wn   = w & 1;
    const int r31  = lane & 31;
    const int h    = lane >> 5;

    const int bn0 = blockIdx.x * 128;
    const int bm0 = blockIdx.y * 128;

    f32x16 acc[2][2];
#pragma unroll
    for (int i = 0; i < 2; ++i)
#pragma unroll
        for (int j = 0; j < 2; ++j)
            acc[i][j] = (f32x16)(0.0f);

    // staging: wave w stages rows [w*32, w*32+32), 2 issues of 16 rows x 64B per mat.
    // lane slot = local_row*4 + g''; fetch global granule g = g'' ^ ((row>>1)&3)
    const int srow = lane >> 2;
    const int scol = (((lane & 3) ^ ((lane >> 3) & 3)) << 4);
    const uint8_t* Ag = A + (size_t)(bm0 + w * 32 + srow) * K_DIM + scol;
    const uint8_t* Bg = B + (size_t)(bn0 + w * 32 + srow) * K_DIM + scol;
    uint8_t* Asw = As + w * 2048;
    uint8_t* Bsw = Bs + w * 2048;

#define STAGE(koff, boff)                                                        \
    do {                                                                         \
        const uint8_t* ag_ = Ag + (koff);                                        \
        const uint8_t* bg_ = Bg + (koff);                                        \
        __builtin_amdgcn_global_load_lds(                                        \
            (const __attribute__((address_space(1))) void*)(ag_),                \
            (__attribute__((address_space(3))) void*)(Asw + (boff)), 16, 0, 0);  \
        __builtin_amdgcn_global_load_lds(                                        \
            (const __attribute__((address_space(1))) void*)(ag_ + (size_t)16 * K_DIM), \
            (__attribute__((address_space(3))) void*)(Asw + (boff) + 1024), 16, 0, 0); \
        __builtin_amdgcn_global_load_lds(                                        \
            (const __attribute__((address_space(1))) void*)(bg_),                \
            (__attribute__((address_space(3))) void*)(Bsw + (boff)), 16, 0, 0);  \
        __builtin_amdgcn_global_load_lds(                                        \
            (const __attribute__((address_space(1))) void*)(bg_ + (size_t)16 * K_DIM), \
            (__attribute__((address_space(3))) void*)(Bsw + (boff) + 1024), 16, 0, 0); \
    } while (0)

    // swizzled, kt-invariant fragment addresses (buf0; buf1 = +16384)
    const int sx = (r31 >> 1) & 3;
    const uint8_t* pa_lo[2]; const uint8_t* pa_hi[2];
    const uint8_t* pb_lo[2]; const uint8_t* pb_hi[2];
#pragma unroll
    for (int mi = 0; mi < 2; ++mi) {
        const uint8_t* base = As + (wm * 64 + mi * 32 + r31) * 64;
        pa_lo[mi] = base + (((2 * h)     ^ sx) << 4);
        pa_hi[mi] = base + (((2 * h + 1) ^ sx) << 4);
    }
#pragma unroll
    for (int ni = 0; ni < 2; ++ni) {
        const uint8_t* base = Bs + (wn * 64 + ni * 32 + r31) * 64;
        pb_lo[ni] = base + (((2 * h)     ^ sx) << 4);
        pb_hi[ni] = base + (((2 * h + 1) ^ sx) << 4);
    }

    auto compute = [&](int off) {
        i32x8 af[2], bf[2];
#pragma unroll
        for (int mi = 0; mi < 2; ++mi) {
            i32x4 lo = *(const i32x4*)(pa_lo[mi] + off);
            i32x4 hi = *(const i32x4*)(pa_hi[mi] + off);
            af[mi] = __builtin_shufflevector(lo, hi, 0, 1, 2, 3, 4, 5, 6, 7);
        }
#pragma unroll
        for (int ni = 0; ni < 2; ++ni) {
            i32x4 lo = *(const i32x4*)(pb_lo[ni] + off);
            i32x4 hi = *(const i32x4*)(pb_hi[ni] + off);
            bf[ni] = __builtin_shufflevector(lo, hi, 0, 1, 2, 3, 4, 5, 6, 7);
        }
#pragma unroll
        for (int mi = 0; mi < 2; ++mi)
#pragma unroll
            for (int ni = 0; ni < 2; ++ni)
                acc[mi][ni] = __builtin_amdgcn_mfma_scale_f32_32x32x64_f8f6f4(
                    af[mi], bf[ni], acc[mi][ni],
                    1, 1,                 // cbsz=bf8(e5m2), blgp=bf8(e5m2)
                    0, 0x7F7F7F7F,        // scale A = 2^0
                    0, 0x7F7F7F7F);       // scale B = 2^0
    };

    const int NT = K_DIM / BK;   // 66 (even)
    STAGE(0, 0);                 // tile 0 -> buf0
    for (int kt = 0; kt < NT; kt += 2) {
        // even phase: prefetch tile kt+1 -> buf1 (kt+1 < NT always), compute buf0
        STAGE((kt + 1) * BK, 16384);
        WAIT_VM4();              // own tile-kt loads done; prefetch in flight
        RAW_BARRIER();           // all waves' tile-kt loads done
        compute(0);
        RAW_BARRIER();           // all waves finished reading buf0 before overwrite

        // odd phase: prefetch tile kt+2 -> buf0 (unless last), compute buf1
        if (kt + 2 < NT) {
            STAGE((kt + 2) * BK, 0);
            WAIT_VM4();
        } else {
            WAIT_VM0();
        }
        RAW_BARRIER();
        compute(16384);
        RAW_BARRIER();
    }
#undef STAGE

    const float sc = scale[0];
#pragma unroll
    for (int ni = 0; ni < 2; ++ni) {
        const int col = bn0 + wn * 64 + ni * 32 + r31;
        const float bv = bias[col];
#pragma unroll
        for (int mi = 0; mi < 2; ++mi) {
            const int rbase = bm0 + wm * 64 + mi * 32 + 4 * h;
#pragma unroll
            for (int reg = 0; reg < 16; ++reg) {
                const int row = rbase + (reg & 3) + 8 * (reg >> 2);
                C[(size_t)row * N_DIM + col] = sc * acc[mi][ni][reg] + bv;
            }
        }
    }
}

extern "C" void kernel_launch(void* const* d_in, const int* in_sizes, int n_in,
                              void* d_out, int out_size, void* d_ws, size_t ws_size,
                              hipStream_t stream) {
    const int*   A_packed = (const int*)d_in[0];
    const int*   SFA      = (const int*)d_in[1];
    const float* scale    = (const float*)d_in[2];
    const int*   B_packed = (const int*)d_in[3];
    const int*   SFB      = (const int*)d_in[4];
    const float* bias     = (const float*)d_in[5];
    float*       out      = (float*)d_out;

    uint8_t* Abf8 = (uint8_t*)d_ws;
    uint8_t* Bbf8 = Abf8 + (size_t)M_DIM * K_DIM;

    const int nblkA = M_DIM * K_DIM / 16;   // 2,162,688 (8448 blocks of 256)
    const int nblkB = N_DIM * K_DIM / 16;   // 1,081,344 (4224 blocks)
    dequant_all<<<(nblkA + nblkB) / 256, 256, 0, stream>>>(
        A_packed, SFA, Abf8, B_packed, SFB, Bbf8);

    dim3 grid(N_DIM / 128, M_DIM / 128);
    gemm_mx<<<grid, 256, 0, stream>>>(Abf8, Bbf8, scale, bias, out);
}